// Round 1
// baseline (5287.874 us; speedup 1.0000x reference)
//
#include <hip/hip_runtime.h>
#include <math.h>

#define T_TASKS 64
#define NS 75
#define NW 5
#define NTOT 375
#define NQ 150
#define DIM 4096
#define QP_ITERS 15
#define SIGMA 0.1f
#define CREG 0.1f

// workspace layout (float offsets)
#define OFF_K   0u          // 64*5625            = 360000
#define OFF_W   360000u     // 64*5*5625          = 1800000
#define OFF_Z   2160000u    // 24000
#define OFF_S   2184000u    // 24000
#define OFF_LAM 2208000u    // 24000
#define OFF_NU  2232000u    // 4800
#define OFF_TV  2236800u    // 24000
#define OFF_V   2260800u    // 64*5*4096          = 1310720  (ends 3571520 floats = 14.3 MB)

// ---------------------------------------------------------------- init state
__global__ void qp_init(float* __restrict__ z, float* __restrict__ s,
                        float* __restrict__ lam, float* __restrict__ nu) {
    int idx = blockIdx.x * 256 + threadIdx.x;
    if (idx < T_TASKS * NTOT) { z[idx] = 0.f; s[idx] = 1.f; lam[idx] = 1.f; }
    if (idx < T_TASKS * NS) nu[idx] = 0.f;
}

// ------------------------------------------------- K[b] = support support^T
// grid (5 rowtiles, 64 tasks), block 256 (16x16). 15 rows x 75 cols per block.
__global__ __launch_bounds__(256) void gram_kernel(const float* __restrict__ support,
                                                   float* __restrict__ Kg) {
    int rt = blockIdx.x, b = blockIdx.y;
    __shared__ float Ss[NS * 68];   // 75 rows x 64-chunk, stride 68 (pad, 16B-aligned)
    int tid = threadIdx.x;
    int tx = tid & 15, ty = tid >> 4;
    int row = rt * 15 + ty;         // valid when ty < 15
    float acc[5] = {0.f, 0.f, 0.f, 0.f, 0.f};
    const float* sb = support + (size_t)b * NS * DIM;
    for (int ch = 0; ch < DIM / 64; ch++) {
        __syncthreads();
        for (int idx = tid; idx < NS * 64; idx += 256) {
            int r = idx >> 6, dd = idx & 63;
            Ss[r * 68 + dd] = sb[(size_t)r * DIM + ch * 64 + dd];
        }
        __syncthreads();
        if (ty < 15) {
            for (int d4 = 0; d4 < 16; d4++) {
                float4 a = *(const float4*)&Ss[row * 68 + d4 * 4];
#pragma unroll
                for (int k = 0; k < 5; k++) {
                    int c = tx + 16 * k;
                    if (c < NS) {
                        float4 bv = *(const float4*)&Ss[c * 68 + d4 * 4];
                        acc[k] += a.x * bv.x + a.y * bv.y + a.z * bv.z + a.w * bv.w;
                    }
                }
            }
        }
    }
    if (ty < 15) {
#pragma unroll
        for (int k = 0; k < 5; k++) {
            int c = tx + 16 * k;
            if (c < NS) Kg[(size_t)b * 5625 + row * 75 + c] = acc[k];
        }
    }
}

// ------------------------------------- per (task, way): residual slice, H_w,
// Cholesky, explicit inverse W_w = H_w^-1, t_w = W_w r1_w.
// grid (5 ways, 64 tasks), block 256.
__global__ __launch_bounds__(256) void factor_kernel(
        const float* __restrict__ Kg, const int* __restrict__ labels,
        const float* __restrict__ zg, const float* __restrict__ sg,
        const float* __restrict__ lamg, const float* __restrict__ nug,
        float* __restrict__ Wg, float* __restrict__ tv) {
    int w = blockIdx.x, b = blockIdx.y;
    int tid = threadIdx.x;
    __shared__ float Hb[75 * 76];
    __shared__ float Vb[75 * 76];
    __shared__ float zw[75], sw[75], lw[75], nuw[75], r1w[75], dgv[75];
    __shared__ float red[256];

    const float* Kt = Kg + (size_t)b * 5625;
    for (int idx = tid; idx < 5625; idx += 256)
        Hb[(idx / 75) * 76 + (idx % 75)] = Kt[idx];
    if (tid < 75) {
        zw[tid]  = zg[b * NTOT + tid * NW + w];
        sw[tid]  = sg[b * NTOT + tid * NW + w];
        lw[tid]  = lamg[b * NTOT + tid * NW + w];
        nuw[tid] = nug[b * NS + tid];
    }
    // mu = mean(lam * s) over all 375 entries of this task
    float part = 0.f;
    for (int idx = tid; idx < NTOT; idx += 256)
        part += lamg[b * NTOT + idx] * sg[b * NTOT + idx];
    red[tid] = part;
    __syncthreads();
    for (int st = 128; st > 0; st >>= 1) { if (tid < st) red[tid] += red[tid + st]; __syncthreads(); }
    float mu = red[0] * (1.f / (float)NTOT);

    // residual r1 for this way-slice; add diagonal to build H_w in place
    if (tid < 75) {
        int labv = labels[b * NS + tid];
        float e = (labv == w) ? -1.f : 0.f;
        float h = (labv == w) ? CREG : 0.f;
        float gz = 0.f;
        for (int j = 0; j < 75; j++) gz += Hb[tid * 76 + j] * zw[j];
        gz += zw[tid];                       // + I z  (G = K blockdiag + I)
        float rz = gz + e + lw[tid] + nuw[tid];
        float rs = zw[tid] + sw[tid] - h;
        r1w[tid] = -rz - (lw[tid] * rs - lw[tid] * sw[tid] + SIGMA * mu) / sw[tid];
        Hb[tid * 76 + tid] += 1.f + lw[tid] / sw[tid];   // + I + diag(D_w)
    }
    for (int idx = tid; idx < 5625; idx += 256) {
        int i = idx / 75, j = idx % 75;
        Vb[i * 76 + j] = (i == j) ? 1.f : 0.f;
    }
    __syncthreads();

    // Cholesky (lower, in place; diag kept in dgv to avoid in-step races)
    for (int k = 0; k < 75; k++) {
        float dkk = sqrtf(Hb[k * 76 + k]);
        if (tid == 0) dgv[k] = dkk;
        float rinv = 1.f / dkk;
        for (int i = k + 1 + tid; i < 75; i += 256) Hb[i * 76 + k] *= rinv;
        __syncthreads();
        int m = 74 - k;
        for (int t2 = tid; t2 < m * m; t2 += 256) {
            int i = k + 1 + t2 / m, j = k + 1 + t2 % m;
            Hb[i * 76 + j] -= Hb[i * 76 + k] * Hb[j * 76 + k];
        }
        __syncthreads();
    }
    // Y = L^-1 via row-sweep forward substitution on identity
    for (int k = 0; k < 75; k++) {
        float dinv = 1.f / dgv[k];
        for (int c = tid; c < 75; c += 256) Vb[k * 76 + c] *= dinv;
        __syncthreads();
        int m = 74 - k;
        for (int t2 = tid; t2 < m * 75; t2 += 256) {
            int i = k + 1 + t2 / 75, c = t2 % 75;
            Vb[i * 76 + c] -= Hb[i * 76 + k] * Vb[k * 76 + c];
        }
        __syncthreads();
    }
    // W = Y^T Y = H^-1 (into Hb; L no longer needed)
    for (int idx = tid; idx < 5625; idx += 256) {
        int i = idx / 75, j = idx % 75;
        int r0 = (i > j) ? i : j;
        float a2 = 0.f;
        for (int r = r0; r < 75; r++) a2 += Vb[r * 76 + i] * Vb[r * 76 + j];
        Hb[i * 76 + j] = a2;
    }
    __syncthreads();
    float* Wrow = Wg + (size_t)(b * NW + w) * 5625;
    for (int idx = tid; idx < 5625; idx += 256)
        Wrow[idx] = Hb[(idx / 75) * 76 + idx % 75];
    if (tid < 75) {
        float a2 = 0.f;
        for (int j = 0; j < 75; j++) a2 += Hb[tid * 76 + j] * r1w[j];
        tv[(b * NW + w) * 75 + tid] = a2;
    }
}

// ------------------------- per task: Schur solve for dnu, then full update.
// grid 64 tasks, block 384.
__global__ __launch_bounds__(384) void schur_update_kernel(
        const int* __restrict__ labels,
        float* __restrict__ z, float* __restrict__ s,
        float* __restrict__ lam, float* __restrict__ nu,
        const float* __restrict__ Wg, const float* __restrict__ tv) {
    int b = blockIdx.x;
    int tid = threadIdx.x;
    __shared__ float Sb[75 * 76];
    __shared__ float zl[NTOT], sl[NTOT], ll[NTOT], tvl[NTOT];
    __shared__ float nul[75], rhs[75], dgv[75];
    __shared__ float red[512];

    if (tid < NTOT) {
        zl[tid] = z[b * NTOT + tid];
        sl[tid] = s[b * NTOT + tid];
        ll[tid] = lam[b * NTOT + tid];
        int i = tid / 5, w = tid % 5;
        tvl[tid] = tv[(b * NW + w) * 75 + i];
    }
    if (tid < 75) nul[tid] = nu[b * NS + tid];
    float part = (tid < NTOT) ? ll[tid] * sl[tid] : 0.f;
    red[tid] = part;
    if (tid < 128) red[384 + tid] = 0.f;
    __syncthreads();
    for (int st = 256; st > 0; st >>= 1) { if (tid < st) red[tid] += red[tid + st]; __syncthreads(); }
    float mu = red[0] * (1.f / (float)NTOT);

    // S = sum_w W_w ; rhs = ra + sum_w t_w
    const float* Wb = Wg + (size_t)b * NW * 5625;
    for (int idx = tid; idx < 5625; idx += 384) {
        float acc = 0.f;
#pragma unroll
        for (int w = 0; w < 5; w++) acc += Wb[w * 5625 + idx];
        Sb[(idx / 75) * 76 + (idx % 75)] = acc;
    }
    if (tid < 75) {
        float ra = 0.f, ts = 0.f;
#pragma unroll
        for (int w = 0; w < 5; w++) { ra += zl[tid * 5 + w]; ts += tvl[tid * 5 + w]; }
        rhs[tid] = ra + ts;
    }
    __syncthreads();

    // Cholesky of S
    for (int k = 0; k < 75; k++) {
        float dkk = sqrtf(Sb[k * 76 + k]);
        if (tid == 0) dgv[k] = dkk;
        float rinv = 1.f / dkk;
        for (int i = k + 1 + tid; i < 75; i += 384) Sb[i * 76 + k] *= rinv;
        __syncthreads();
        int m = 74 - k;
        for (int t2 = tid; t2 < m * m; t2 += 384) {
            int i = k + 1 + t2 / m, j = k + 1 + t2 % m;
            Sb[i * 76 + j] -= Sb[i * 76 + k] * Sb[j * 76 + k];
        }
        __syncthreads();
    }
    // forward solve L y = rhs
    for (int k = 0; k < 75; k++) {
        if (tid == 0) rhs[k] /= dgv[k];
        __syncthreads();
        for (int i = k + 1 + tid; i < 75; i += 384) rhs[i] -= Sb[i * 76 + k] * rhs[k];
        __syncthreads();
    }
    // back solve L^T dnu = y
    for (int k = 74; k >= 0; k--) {
        if (tid == 0) rhs[k] /= dgv[k];
        __syncthreads();
        for (int i = tid; i < k; i += 384) rhs[i] -= Sb[k * 76 + i] * rhs[k];
        __syncthreads();
    }

    // dz, ds, dlam, step length, state update
    float dz_t = 0.f, ds_t = 0.f, dl_t = 0.f, rat = INFINITY;
    if (tid < NTOT) {
        int i = tid / 5, w = tid % 5;
        const float* Wrow = Wb + w * 5625 + i * 75;
        float acc = 0.f;
        for (int j = 0; j < 75; j++) acc += Wrow[j] * rhs[j];
        dz_t = tvl[tid] - acc;
        int labv = labels[b * NS + i];
        float h = (labv == w) ? CREG : 0.f;
        float rs = zl[tid] + sl[tid] - h;
        ds_t = -rs - dz_t;
        dl_t = (ll[tid] * dz_t + ll[tid] * rs - ll[tid] * sl[tid] + SIGMA * mu) / sl[tid];
        float r1 = (ds_t < 0.f) ? (-sl[tid] / ds_t) : INFINITY;
        float r2 = (dl_t < 0.f) ? (-ll[tid] / dl_t) : INFINITY;
        rat = fminf(r1, r2);
    }
    red[tid] = rat;
    if (tid < 128) red[384 + tid] = INFINITY;
    __syncthreads();
    for (int st = 256; st > 0; st >>= 1) { if (tid < st) red[tid] = fminf(red[tid], red[tid + st]); __syncthreads(); }
    float alpha = fminf(1.f, 0.99f * red[0]);
    if (tid < NTOT) {
        z[b * NTOT + tid]   = zl[tid] + alpha * dz_t;
        s[b * NTOT + tid]   = sl[tid] + alpha * ds_t;
        lam[b * NTOT + tid] = ll[tid] + alpha * dl_t;
    }
    if (tid < 75) nu[b * NS + tid] = nul[tid] + alpha * rhs[tid];
}

// ------------------------------ v[b,w,:] = sum_s z[b,s,w] * support[b,s,:]
// grid (16 d-chunks, 64 tasks), block 256.
__global__ __launch_bounds__(256) void v_kernel(const float* __restrict__ support,
                                                const float* __restrict__ z,
                                                float* __restrict__ vbuf) {
    int dc = blockIdx.x, b = blockIdx.y;
    __shared__ float zs[NTOT];
    int tid = threadIdx.x;
    for (int idx = tid; idx < NTOT; idx += 256) zs[idx] = z[b * NTOT + idx];
    __syncthreads();
    int d = dc * 256 + tid;
    float acc[5] = {0.f, 0.f, 0.f, 0.f, 0.f};
    const float* sb = support + (size_t)b * NS * DIM + d;
    for (int ss = 0; ss < NS; ss++) {
        float sv = sb[(size_t)ss * DIM];
#pragma unroll
        for (int w = 0; w < 5; w++) acc[w] += sv * zs[ss * 5 + w];
    }
#pragma unroll
    for (int w = 0; w < 5; w++) vbuf[(size_t)(b * NW + w) * DIM + d] = acc[w];
}

// -------------------- logits[b,q,w] = sum_d query[b,q,d] * v[b,w,d]
// grid (5 query-tiles of 30, 64 tasks), block 256 (4 waves, 8 rows each).
__global__ __launch_bounds__(256) void logits_kernel(const float* __restrict__ query,
                                                     const float* __restrict__ vbuf,
                                                     float* __restrict__ out) {
    int qt = blockIdx.x, b = blockIdx.y;
    __shared__ float vs[5 * 1028];
    int tid = threadIdx.x;
    int lane = tid & 63, wid = tid >> 6;
    float acc[8][5];
#pragma unroll
    for (int r = 0; r < 8; r++)
#pragma unroll
        for (int w = 0; w < 5; w++) acc[r][w] = 0.f;

    for (int c = 0; c < 4; c++) {
        __syncthreads();
        for (int idx = tid; idx < 5120; idx += 256) {
            int w = idx >> 10, dd = idx & 1023;
            vs[w * 1028 + dd] = vbuf[(size_t)(b * NW + w) * DIM + c * 1024 + dd];
        }
        __syncthreads();
#pragma unroll
        for (int ri = 0; ri < 8; ri++) {
            int r = wid + ri * 4;
            if (r < 30) {
                int q = qt * 30 + r;
                const float* qp = query + (size_t)(b * NQ + q) * DIM + c * 1024;
#pragma unroll
                for (int j = 0; j < 4; j++) {
                    int d = lane * 4 + j * 256;
                    float4 qv = *(const float4*)(qp + d);
#pragma unroll
                    for (int w = 0; w < 5; w++) {
                        float4 vv = *(const float4*)(&vs[w * 1028 + d]);
                        acc[ri][w] += qv.x * vv.x + qv.y * vv.y + qv.z * vv.z + qv.w * vv.w;
                    }
                }
            }
        }
    }
#pragma unroll
    for (int ri = 0; ri < 8; ri++) {
        int r = wid + ri * 4;
#pragma unroll
        for (int w = 0; w < 5; w++) {
            float v = acc[ri][w];
            for (int off = 32; off > 0; off >>= 1) v += __shfl_xor(v, off, 64);
            if (r < 30 && lane == 0)
                out[(size_t)(b * NQ + qt * 30 + r) * NW + w] = v;
        }
    }
}

// ---------------------------------------------------------------------------
extern "C" void kernel_launch(void* const* d_in, const int* in_sizes, int n_in,
                              void* d_out, int out_size, void* d_ws, size_t ws_size,
                              hipStream_t stream) {
    const float* query   = (const float*)d_in[0];
    const float* support = (const float*)d_in[1];
    const int*   labels  = (const int*)d_in[2];
    float* out = (float*)d_out;
    float* ws  = (float*)d_ws;

    float* Kg   = ws + OFF_K;
    float* Wg   = ws + OFF_W;
    float* z    = ws + OFF_Z;
    float* s    = ws + OFF_S;
    float* lam  = ws + OFF_LAM;
    float* nu   = ws + OFF_NU;
    float* tv   = ws + OFF_TV;
    float* vbuf = ws + OFF_V;

    qp_init<<<(T_TASKS * NTOT + 255) / 256, 256, 0, stream>>>(z, s, lam, nu);
    gram_kernel<<<dim3(5, T_TASKS), 256, 0, stream>>>(support, Kg);
    for (int it = 0; it < QP_ITERS; it++) {
        factor_kernel<<<dim3(NW, T_TASKS), 256, 0, stream>>>(Kg, labels, z, s, lam, nu, Wg, tv);
        schur_update_kernel<<<T_TASKS, 384, 0, stream>>>(labels, z, s, lam, nu, Wg, tv);
    }
    v_kernel<<<dim3(16, T_TASKS), 256, 0, stream>>>(support, z, vbuf);
    logits_kernel<<<dim3(5, T_TASKS), 256, 0, stream>>>(query, vbuf, out);
}

// Round 2
// 3326.103 us; speedup vs baseline: 1.5898x; 1.5898x over previous
//
#include <hip/hip_runtime.h>
#include <math.h>

#define T_TASKS 64
#define NS 75
#define NW 5
#define NTOT 375
#define NQ 150
#define DIM 4096
#define QP_ITERS 15
#define SIGMA 0.1f
#define CREG 0.1f

// workspace layout (float offsets)
#define OFF_K   0u          // 64*5625            = 360000
#define OFF_W   360000u     // 64*5*5625          = 1800000
#define OFF_KP  360000u     // gram partials (4*360000) alias W: W dead until first factor
#define OFF_Z   2160000u
#define OFF_S   2184000u
#define OFF_LAM 2208000u
#define OFF_NU  2232000u
#define OFF_TV  2236800u
#define OFF_V   2260800u    // ends 3571520 floats = 14.3 MB

// ---------------------------------------------------------------- init state
__global__ void qp_init(float* __restrict__ z, float* __restrict__ s,
                        float* __restrict__ lam, float* __restrict__ nu) {
    int idx = blockIdx.x * 256 + threadIdx.x;
    if (idx < T_TASKS * NTOT) { z[idx] = 0.f; s[idx] = 1.f; lam[idx] = 1.f; }
    if (idx < T_TASKS * NS) nu[idx] = 0.f;
}

// ------------------------------------------- K partial over a d-quarter.
// grid (4 quarters, 64 tasks), block 256. 15x15 threads each own a 5x5 tile.
__global__ __launch_bounds__(256) void gram_partial(const float* __restrict__ support,
                                                    float* __restrict__ Kp) {
    int qd = blockIdx.x, b = blockIdx.y;
    __shared__ __align__(16) float Ss[NS * 68];
    int tid = threadIdx.x;
    int tx = tid & 15, ty = tid >> 4;
    bool act = (tx < 15) && (ty < 15);
    float acc[5][5];
#pragma unroll
    for (int u = 0; u < 5; u++)
#pragma unroll
        for (int v = 0; v < 5; v++) acc[u][v] = 0.f;
    const float* sb = support + (size_t)b * NS * DIM + qd * 1024;
    for (int ch = 0; ch < 16; ch++) {
        __syncthreads();
        for (int idx = tid; idx < NS * 16; idx += 256) {
            int r = idx >> 4, d4 = idx & 15;
            *(float4*)&Ss[r * 68 + d4 * 4] =
                *(const float4*)&sb[(size_t)r * DIM + ch * 64 + d4 * 4];
        }
        __syncthreads();
        if (act) {
            for (int d4 = 0; d4 < 16; d4++) {
                float4 av[5], bv[5];
#pragma unroll
                for (int u = 0; u < 5; u++) av[u] = *(const float4*)&Ss[(ty * 5 + u) * 68 + d4 * 4];
#pragma unroll
                for (int v = 0; v < 5; v++) bv[v] = *(const float4*)&Ss[(tx * 5 + v) * 68 + d4 * 4];
#pragma unroll
                for (int u = 0; u < 5; u++)
#pragma unroll
                    for (int v = 0; v < 5; v++)
                        acc[u][v] += av[u].x * bv[v].x + av[u].y * bv[v].y +
                                     av[u].z * bv[v].z + av[u].w * bv[v].w;
            }
        }
    }
    if (act) {
        float* Ko = Kp + (size_t)(qd * T_TASKS + b) * 5625;
#pragma unroll
        for (int u = 0; u < 5; u++)
#pragma unroll
            for (int v = 0; v < 5; v++)
                Ko[(ty * 5 + u) * 75 + tx * 5 + v] = acc[u][v];
    }
}

__global__ void gram_reduce(const float* __restrict__ Kp, float* __restrict__ Kg) {
    int idx = blockIdx.x * 256 + threadIdx.x;
    if (idx < T_TASKS * 5625)
        Kg[idx] = Kp[idx] + Kp[360000u + idx] + Kp[720000u + idx] + Kp[1080000u + idx];
}

// ------------------------------------- per (task, way): residual slice, H_w,
// Cholesky (1 barrier/step, triangular, division-free), Y=L^-1 (transposed),
// W = Y^T Y via contiguous float4 dots, t_w = Y^T (Y r1).
__global__ __launch_bounds__(256) void factor_kernel(
        const float* __restrict__ Kg, const int* __restrict__ labels,
        const float* __restrict__ zg, const float* __restrict__ sg,
        const float* __restrict__ lamg, const float* __restrict__ nug,
        float* __restrict__ Wg, float* __restrict__ tv) {
    int w = blockIdx.x, b = blockIdx.y;
    int tid = threadIdx.x;
    int tx = tid & 15, ty = tid >> 4;
    __shared__ __align__(16) float Hb[75 * 76];
    __shared__ __align__(16) float Vt[75 * 76];   // Vt[c*76+r] = Ytilde[r][c]
    __shared__ __align__(16) float zw[76];
    __shared__ __align__(16) float r1w[76];
    __shared__ __align__(16) float dgv[76];       // rinv_k = 1/sqrt(Hkk)
    __shared__ __align__(16) float y2[76];
    __shared__ float red[256];

    const float* Kt = Kg + (size_t)b * 5625;
    for (int idx = tid; idx < 5625; idx += 256)
        Hb[(idx / 75) * 76 + (idx % 75)] = Kt[idx];
    if (tid < 75) Hb[tid * 76 + 75] = 0.f;
    for (int idx = tid; idx < 75 * 76; idx += 256)
        Vt[idx] = ((idx / 76) == (idx % 76)) ? 1.f : 0.f;
    float sv = 1.f, lv = 1.f, nuv = 0.f;
    if (tid < 75) {
        zw[tid] = zg[b * NTOT + tid * NW + w];
        sv  = sg[b * NTOT + tid * NW + w];
        lv  = lamg[b * NTOT + tid * NW + w];
        nuv = nug[b * NS + tid];
    } else if (tid == 75) zw[75] = 0.f;
    float part = 0.f;
    for (int idx = tid; idx < NTOT; idx += 256)
        part += lamg[b * NTOT + idx] * sg[b * NTOT + idx];
    red[tid] = part;
    __syncthreads();
    for (int st = 128; st > 0; st >>= 1) { if (tid < st) red[tid] += red[tid + st]; __syncthreads(); }
    float mu = red[0] * (1.f / (float)NTOT);

    if (tid < 75) {
        int labv = labels[b * NS + tid];
        float e = (labv == w) ? -1.f : 0.f;
        float h = (labv == w) ? CREG : 0.f;
        const float4* hr = (const float4*)&Hb[tid * 76];
        const float4* zz = (const float4*)zw;
        float gz = 0.f;
#pragma unroll
        for (int r4 = 0; r4 < 19; r4++) {
            float4 a4 = hr[r4], z4 = zz[r4];
            gz += a4.x * z4.x + a4.y * z4.y + a4.z * z4.z + a4.w * z4.w;
        }
        gz += zw[tid];                        // + I z
        float rz = gz + e + lv + nuv;
        float rs = zw[tid] + sv - h;
        r1w[tid] = -rz - (lv * rs - lv * sv + SIGMA * mu) / sv;
        Hb[tid * 76 + tid] += 1.f + lv / sv;  // + I + diag(D_w)
    }
    __syncthreads();

    // Cholesky, lower triangle, unscaled columns: H[i][j] -= H[i][k]H[j][k]/Hkk
    for (int k = 0; k < 75; k++) {
        float Hkk = Hb[k * 76 + k];
        float rinv = 1.f / sqrtf(Hkk);
        if (tid == 0) dgv[k] = rinv;
        float r2 = rinv * rinv;
        for (int i = k + 1 + ty; i < 75; i += 16) {
            float Li = Hb[i * 76 + k] * r2;
            for (int j = k + 1 + tx; j <= i; j += 16)
                Hb[i * 76 + j] -= Li * Hb[j * 76 + k];
        }
        __syncthreads();
    }
    if (tid == 0) dgv[75] = 0.f;

    // Ytilde sweep (1 barrier/step): Yt[i][:] -= H[i][k]*rinv_k^2 * Yt[k][:]
    for (int k = 0; k < 75; k++) {
        float s2 = dgv[k] * dgv[k];
        for (int i = k + 1 + ty; i < 75; i += 16) {
            float f = Hb[i * 76 + k] * s2;
            for (int c = tx; c <= k; c += 16)
                Vt[c * 76 + i] -= f * Vt[c * 76 + k];
        }
        __syncthreads();
    }
    // Y[r][:] = Ytilde[r][:] * rinv_r
    for (int idx = tid; idx < 75 * 76; idx += 256)
        Vt[idx] *= dgv[idx % 76];
    __syncthreads();

    // W lower triangle: W[i][j] = <Vt row i, Vt row j>; stage into Hb
    for (int t2 = tid; t2 < 2850; t2 += 256) {
        int i = (int)((sqrtf(8.f * (float)t2 + 1.f) - 1.f) * 0.5f);
        int base = (i * (i + 1)) >> 1;
        if (base > t2) { i--; base = (i * (i + 1)) >> 1; }
        else if (t2 - base > i) { i++; base = (i * (i + 1)) >> 1; }
        int j = t2 - base;
        const float4* vi = (const float4*)&Vt[i * 76];
        const float4* vj = (const float4*)&Vt[j * 76];
        float a2 = 0.f;
#pragma unroll
        for (int r4 = 0; r4 < 19; r4++) {
            float4 x = vi[r4], y = vj[r4];
            a2 += x.x * y.x + x.y * y.y + x.z * y.z + x.w * y.w;
        }
        Hb[i * 76 + j] = a2;
        if (i != j) Hb[j * 76 + i] = a2;
    }
    // y2 = Y r1
    if (tid < 75) {
        float a2 = 0.f;
        for (int c = 0; c < 75; c++) a2 += Vt[c * 76 + tid] * r1w[c];
        y2[tid] = a2;
    } else if (tid == 75) y2[75] = 0.f;
    __syncthreads();

    float* Wrow = Wg + (size_t)(b * NW + w) * 5625;
    for (int idx = tid; idx < 5625; idx += 256)
        Wrow[idx] = Hb[(idx / 75) * 76 + (idx % 75)];
    if (tid < 75) {   // t = Y^T y2
        const float4* vi = (const float4*)&Vt[tid * 76];
        const float4* yy = (const float4*)y2;
        float a2 = 0.f;
#pragma unroll
        for (int r4 = 0; r4 < 19; r4++) {
            float4 x = vi[r4], z4 = yy[r4];
            a2 += x.x * z4.x + x.y * z4.y + x.z * z4.z + x.w * z4.w;
        }
        tv[(b * NW + w) * 75 + tid] = a2;
    }
}

// ------------------------- per task: Schur solve for dnu, then full update.
__global__ __launch_bounds__(384) void schur_update_kernel(
        const int* __restrict__ labels,
        float* __restrict__ z, float* __restrict__ s,
        float* __restrict__ lam, float* __restrict__ nu,
        const float* __restrict__ Wg, const float* __restrict__ tv) {
    int b = blockIdx.x;
    int tid = threadIdx.x;
    int tx = tid & 15, ty = tid >> 4;   // 24 x 16
    __shared__ float Sb[75 * 76];
    __shared__ float zl[NTOT], sl[NTOT], ll[NTOT], tvl[NTOT];
    __shared__ float nul[75], rhs[75], dgv[75];
    __shared__ float red[512];

    if (tid < NTOT) {
        zl[tid] = z[b * NTOT + tid];
        sl[tid] = s[b * NTOT + tid];
        ll[tid] = lam[b * NTOT + tid];
        int i = tid / 5, w = tid % 5;
        tvl[tid] = tv[(b * NW + w) * 75 + i];
    }
    if (tid < 75) nul[tid] = nu[b * NS + tid];
    float part = (tid < NTOT) ? ll[tid] * sl[tid] : 0.f;
    red[tid] = part;
    if (tid < 128) red[384 + tid] = 0.f;
    __syncthreads();
    for (int st = 256; st > 0; st >>= 1) { if (tid < st) red[tid] += red[tid + st]; __syncthreads(); }
    float mu = red[0] * (1.f / (float)NTOT);

    const float* Wb = Wg + (size_t)b * NW * 5625;
    for (int idx = tid; idx < 5625; idx += 384) {
        float acc = 0.f;
#pragma unroll
        for (int w = 0; w < 5; w++) acc += Wb[w * 5625 + idx];
        Sb[(idx / 75) * 76 + (idx % 75)] = acc;
    }
    if (tid < 75) {
        float ra = 0.f, ts = 0.f;
#pragma unroll
        for (int w = 0; w < 5; w++) { ra += zl[tid * 5 + w]; ts += tvl[tid * 5 + w]; }
        rhs[tid] = ra + ts;
    }
    __syncthreads();

    // Cholesky of S (unscaled columns, 1 barrier/step)
    for (int k = 0; k < 75; k++) {
        float Skk = Sb[k * 76 + k];
        float rinv = 1.f / sqrtf(Skk);
        if (tid == 0) dgv[k] = rinv;
        float r2 = rinv * rinv;
        for (int i = k + 1 + ty; i < 75; i += 24) {
            float Li = Sb[i * 76 + k] * r2;
            for (int j = k + 1 + tx; j <= i; j += 16)
                Sb[i * 76 + j] -= Li * Sb[j * 76 + k];
        }
        __syncthreads();
    }
    // forward: rhs -> ytilde (y[k] = rhs[k]*dgv[k])
    for (int k = 0; k < 75; k++) {
        float f = dgv[k] * dgv[k] * rhs[k];
        for (int i = k + 1 + tid; i < 75; i += 384)
            rhs[i] -= Sb[i * 76 + k] * f;
        __syncthreads();
    }
    if (tid < 75) rhs[tid] *= dgv[tid];   // rhs = y
    __syncthreads();
    // back: L^T x = y, unscaled (x[k] = rhs[k]*dgv[k])
    for (int k = 74; k >= 0; k--) {
        float xk = rhs[k] * dgv[k];
        for (int i = tid; i < k; i += 384)
            rhs[i] -= Sb[k * 76 + i] * dgv[i] * xk;
        __syncthreads();
    }
    if (tid < 75) rhs[tid] *= dgv[tid];   // rhs = dnu step
    __syncthreads();

    float dz_t = 0.f, ds_t = 0.f, dl_t = 0.f, rat = INFINITY;
    if (tid < NTOT) {
        int i = tid / 5, w = tid % 5;
        const float* Wcol = Wb + w * 5625;   // W symmetric: W[i][j] = W[j][i]
        float acc = 0.f;
        for (int j = 0; j < 75; j++) acc += Wcol[j * 75 + i] * rhs[j];
        dz_t = tvl[tid] - acc;
        int labv = labels[b * NS + i];
        float h = (labv == w) ? CREG : 0.f;
        float rs = zl[tid] + sl[tid] - h;
        ds_t = -rs - dz_t;
        dl_t = (ll[tid] * dz_t + ll[tid] * rs - ll[tid] * sl[tid] + SIGMA * mu) / sl[tid];
        float r1 = (ds_t < 0.f) ? (-sl[tid] / ds_t) : INFINITY;
        float r2 = (dl_t < 0.f) ? (-ll[tid] / dl_t) : INFINITY;
        rat = fminf(r1, r2);
    }
    red[tid] = rat;
    if (tid < 128) red[384 + tid] = INFINITY;
    __syncthreads();
    for (int st = 256; st > 0; st >>= 1) { if (tid < st) red[tid] = fminf(red[tid], red[tid + st]); __syncthreads(); }
    float alpha = fminf(1.f, 0.99f * red[0]);
    if (tid < NTOT) {
        z[b * NTOT + tid]   = zl[tid] + alpha * dz_t;
        s[b * NTOT + tid]   = sl[tid] + alpha * ds_t;
        lam[b * NTOT + tid] = ll[tid] + alpha * dl_t;
    }
    if (tid < 75) nu[b * NS + tid] = nul[tid] + alpha * rhs[tid];
}

// ------------------------------ v[b,w,:] = sum_s z[b,s,w] * support[b,s,:]
__global__ __launch_bounds__(256) void v_kernel(const float* __restrict__ support,
                                                const float* __restrict__ z,
                                                float* __restrict__ vbuf) {
    int dc = blockIdx.x, b = blockIdx.y;
    __shared__ float zs[NTOT];
    int tid = threadIdx.x;
    for (int idx = tid; idx < NTOT; idx += 256) zs[idx] = z[b * NTOT + idx];
    __syncthreads();
    int d = dc * 256 + tid;
    float acc[5] = {0.f, 0.f, 0.f, 0.f, 0.f};
    const float* sb = support + (size_t)b * NS * DIM + d;
    for (int ss = 0; ss < NS; ss++) {
        float svv = sb[(size_t)ss * DIM];
#pragma unroll
        for (int w = 0; w < 5; w++) acc[w] += svv * zs[ss * 5 + w];
    }
#pragma unroll
    for (int w = 0; w < 5; w++) vbuf[(size_t)(b * NW + w) * DIM + d] = acc[w];
}

// -------------------- logits[b,q,w] = sum_d query[b,q,d] * v[b,w,d]
__global__ __launch_bounds__(256) void logits_kernel(const float* __restrict__ query,
                                                     const float* __restrict__ vbuf,
                                                     float* __restrict__ out) {
    int qt = blockIdx.x, b = blockIdx.y;
    __shared__ __align__(16) float vs[5 * 1028];
    int tid = threadIdx.x;
    int lane = tid & 63, wid = tid >> 6;
    float acc[8][5];
#pragma unroll
    for (int r = 0; r < 8; r++)
#pragma unroll
        for (int w = 0; w < 5; w++) acc[r][w] = 0.f;

    for (int c = 0; c < 4; c++) {
        __syncthreads();
        for (int idx = tid; idx < 5120; idx += 256) {
            int w = idx >> 10, dd = idx & 1023;
            vs[w * 1028 + dd] = vbuf[(size_t)(b * NW + w) * DIM + c * 1024 + dd];
        }
        __syncthreads();
#pragma unroll
        for (int ri = 0; ri < 8; ri++) {
            int r = wid + ri * 4;
            if (r < 30) {
                int q = qt * 30 + r;
                const float* qp = query + (size_t)(b * NQ + q) * DIM + c * 1024;
#pragma unroll
                for (int j = 0; j < 4; j++) {
                    int d = lane * 4 + j * 256;
                    float4 qv = *(const float4*)(qp + d);
#pragma unroll
                    for (int w = 0; w < 5; w++) {
                        float4 vv = *(const float4*)(&vs[w * 1028 + d]);
                        acc[ri][w] += qv.x * vv.x + qv.y * vv.y + qv.z * vv.z + qv.w * vv.w;
                    }
                }
            }
        }
    }
#pragma unroll
    for (int ri = 0; ri < 8; ri++) {
        int r = wid + ri * 4;
#pragma unroll
        for (int w = 0; w < 5; w++) {
            float v = acc[ri][w];
            for (int off = 32; off > 0; off >>= 1) v += __shfl_xor(v, off, 64);
            if (r < 30 && lane == 0)
                out[(size_t)(b * NQ + qt * 30 + r) * NW + w] = v;
        }
    }
}

// ---------------------------------------------------------------------------
extern "C" void kernel_launch(void* const* d_in, const int* in_sizes, int n_in,
                              void* d_out, int out_size, void* d_ws, size_t ws_size,
                              hipStream_t stream) {
    const float* query   = (const float*)d_in[0];
    const float* support = (const float*)d_in[1];
    const int*   labels  = (const int*)d_in[2];
    float* out = (float*)d_out;
    float* ws  = (float*)d_ws;

    float* Kg   = ws + OFF_K;
    float* Kp   = ws + OFF_KP;
    float* Wg   = ws + OFF_W;
    float* z    = ws + OFF_Z;
    float* s    = ws + OFF_S;
    float* lam  = ws + OFF_LAM;
    float* nu   = ws + OFF_NU;
    float* tv   = ws + OFF_TV;
    float* vbuf = ws + OFF_V;

    qp_init<<<(T_TASKS * NTOT + 255) / 256, 256, 0, stream>>>(z, s, lam, nu);
    gram_partial<<<dim3(4, T_TASKS), 256, 0, stream>>>(support, Kp);
    gram_reduce<<<(T_TASKS * 5625 + 255) / 256, 256, 0, stream>>>(Kp, Kg);
    for (int it = 0; it < QP_ITERS; it++) {
        factor_kernel<<<dim3(NW, T_TASKS), 256, 0, stream>>>(Kg, labels, z, s, lam, nu, Wg, tv);
        schur_update_kernel<<<T_TASKS, 384, 0, stream>>>(labels, z, s, lam, nu, Wg, tv);
    }
    v_kernel<<<dim3(16, T_TASKS), 256, 0, stream>>>(support, z, vbuf);
    logits_kernel<<<dim3(5, T_TASKS), 256, 0, stream>>>(query, vbuf, out);
}